// Round 10
// baseline (599.024 us; speedup 1.0000x reference)
//
#include <hip/hip_runtime.h>
#include <math.h>

// ---------------- problem constants ----------------
#define BB 16
#define CIN 15
#define HW 384
#define XPL 147456             // 384*384
#define NX 35389440            // 16*15*384*384
#define PH 96
#define GW 192
#define YP 98                  // padded Y1 spatial
#define Y1IPL (98*98*64)       // 614656 elems per image
#define OUT_ELEMS (BB*6*PH*PH)

// ws byte offsets (end = 77,594,624 == proven available, round-4 layout)
#define OFF_WG   0             // frag-major [30][4][512] bf16 (BN-folded)
#define OFF_WE1  122880        // frag-major [3][30][4][512] bf16
#define OFF_WH   491520        // frag-major [3][18][24][512] bf16
#define OFF_GSH  1818624       // fp32 [64]
#define OFF_FEAT 1818880       // fp32 [16][64]
#define OFF_IDX  1822976       // int  [16]
#define OFF_CBUF 2097152       // bf16 [16][192][192][64] = 75,497,472 B; Y1 overlays

typedef __attribute__((ext_vector_type(8))) short short8;
typedef __attribute__((ext_vector_type(4))) float floatx4;
typedef __attribute__((ext_vector_type(4))) unsigned int uintx4;
typedef __attribute__((ext_vector_type(2))) unsigned int uintx2;

__device__ __forceinline__ unsigned bf16rne(float f) {
  unsigned u = __float_as_uint(f);
  unsigned r = ((u >> 16) & 1u) + 0x7FFFu;
  return (u + r) >> 16;
}
__device__ __forceinline__ float bf2f(unsigned short s) {
  return __uint_as_float(((unsigned)s) << 16);
}

// ---------------- K0: weight prep (fragment-major) — round-4 verbatim ----------------
__global__ __launch_bounds__(256) void k_prep(
    const float* __restrict__ g_conv_w, const float* __restrict__ e_conv1_w,
    const float* __restrict__ e_head_w1,
    const float* __restrict__ gamma, const float* __restrict__ var,
    const float* __restrict__ beta,  const float* __restrict__ mean,
    unsigned char* __restrict__ wsb)
{
  int i = blockIdx.x * 256 + threadIdx.x;
  unsigned short* Wg  = (unsigned short*)(wsb + OFF_WG);
  unsigned short* We1 = (unsigned short*)(wsb + OFF_WE1);
  unsigned short* Wh  = (unsigned short*)(wsb + OFF_WH);
  float* gsh = (float*)(wsb + OFF_GSH);
  if (i < 61440) {
    int j = i & 7, lane = (i >> 3) & 63, mtc = i >> 9;
    int mt = mtc & 3, c = mtc >> 2, ic = c >> 1, h = c & 1;
    int oc = mt * 16 + (lane & 15), q = lane >> 4;
    int ky = 4 * h + q, kx = j;
    float v = 0.f;
    if (ky < 7 && kx < 7) v = g_conv_w[oc * 735 + ic * 49 + ky * 7 + kx];
    float inv = gamma[oc] * rsqrtf(var[oc] + 1e-5f);
    Wg[i] = (unsigned short)bf16rne(v * inv);
  } else if (i < 245760) {
    int r = i - 61440;
    int e = r / 61440, r2 = r % 61440;
    int j = r2 & 7, lane = (r2 >> 3) & 63, mtc = r2 >> 9;
    int mt = mtc & 3, c = mtc >> 2, ic = c >> 1, h = c & 1;
    int oc = mt * 16 + (lane & 15), q = lane >> 4;
    int ky = 4 * h + q, kx = j;
    float v = 0.f;
    if (ky < 7 && kx < 7) v = e_conv1_w[(e * 64 + oc) * 735 + ic * 49 + ky * 7 + kx];
    We1[r] = (unsigned short)bf16rne(v);
  } else if (i < 909312) {
    int r = i - 245760;
    int e = r / 221184, r2 = r % 221184;
    int j = r2 & 7, lane = (r2 >> 3) & 63, mtc = r2 >> 9;
    int mt = mtc % 24, chunk = mtc / 24;
    int kk = chunk >> 1, ih = chunk & 1;
    int oc = mt * 16 + (lane & 15), q = lane >> 4;
    int ic = ih * 32 + q * 8 + j;
    Wh[r] = (unsigned short)bf16rne(e_head_w1[((e * 384 + oc) * 64 + ic) * 9 + kk]);
  } else if (i < 909376) {
    int oc = i - 909312;
    float inv = gamma[oc] * rsqrtf(var[oc] + 1e-5f);
    gsh[oc] = beta[oc] - mean[oc] * inv;
  }
}

// ---------------- K1: gating conv 7x7 s2 — ic-chunked double-buffered pipeline ------
// ROUND-6 VERBATIM (164 µs). Occupancy ~10 waves/CU here PROTECTS L2 write combining
// (round-7: 512-thr raised occupancy to 58% but WRITE_SIZE 74->302MB -> 271 µs).
__global__ __launch_bounds__(256, 3) void k_gconv(
    const float* __restrict__ x, const unsigned short* __restrict__ Wg,
    const float* __restrict__ gsh, unsigned short* __restrict__ Cbuf)
{
  const int t = threadIdx.x, w = t >> 6, lane = t & 63, q = lane >> 4, ln = lane & 15;

  // XCD-aware bijective swizzle: consecutive tiles (shared halo) -> same XCD L2
  int lin = blockIdx.x + 12 * (blockIdx.y + 12 * blockIdx.z);
  int nl = (lin & 7) * 288 + (lin >> 3);
  const int b = nl / 144; int r144 = nl - b * 144;
  const int by = r144 / 12, bx = r144 - by * 12;

  const int px0 = bx * 16, py0 = by * 16;
  const int iy0 = 2 * py0 - 3, ix0 = 2 * px0 - 3;
  const bool edge = (bx == 0) | (bx == 11) | (by == 0) | (by == 11);
  const int xbase = b * CIN * XPL;

  __shared__ unsigned tilU[2][2280];   // 18,240 B

  // staging task: t < 228 -> (lic 0..2, srow 0..37, half 0..1)
  const bool act = (t < 228);
  const int lic = t / 76, r2 = t - lic * 76, srow = r2 >> 1, half = r2 & 1;
  const int iy = iy0 + srow;
  const int A = ix0 + 20 * half - 1;                 // == 0 (mod 4)
  const unsigned rowm = (iy >= 0 && iy < HW) ? 0xFFFFFFFFu : 0u;
  const int abase = xbase + iy * HW + A;
  const int dloc = (lic * 38 + srow) * 20 + 10 * half;

  floatx4 F[6];

  auto issue = [&](int c) {
    if (!act) return;
    int a = abase + (c * 3 + lic) * XPL;
    if (!edge) {
      const float* src = x + a;
#pragma unroll
      for (int s = 0; s < 6; ++s) F[s] = *(const floatx4*)(src + 4 * s);
    } else {
#pragma unroll
      for (int s = 0; s < 6; ++s) {
        int as = a + 4 * s;
        as = max(as, 0); as = min(as, NX - 4);       // preserves 16B alignment
        F[s] = *(const floatx4*)(x + as);
      }
    }
  };

  auto commit = [&](unsigned* buf) {
    if (!act) return;
    float f[24];
#pragma unroll
    for (int s = 0; s < 6; ++s) {
      f[4*s] = F[s].x; f[4*s+1] = F[s].y; f[4*s+2] = F[s].z; f[4*s+3] = F[s].w;
    }
    unsigned* dst = buf + dloc;
    if (!edge) {
#pragma unroll
      for (int jj = 0; jj < 5; ++jj) {
        uintx2 pr;
        pr.x = bf16rne(f[1 + 4*jj]) | (bf16rne(f[2 + 4*jj]) << 16);
        pr.y = bf16rne(f[3 + 4*jj]) | (bf16rne(f[4 + 4*jj]) << 16);
        *(uintx2*)(dst + 2 * jj) = pr;
      }
    } else {
#pragma unroll
      for (int jj = 0; jj < 5; ++jj) {
        uintx2 pr;
#pragma unroll
        for (int k = 0; k < 2; ++k) {
          int j = 2 * jj + k;
          int cc = A + 1 + 2 * j;
          unsigned m = rowm;
          m &= ((cc >= 0) && (cc < HW)) ? 0xFFFFFFFFu : 0xFFFF0000u;
          m &= ((cc + 1 >= 0) && (cc + 1 < HW)) ? 0xFFFFFFFFu : 0x0000FFFFu;
          unsigned d = (bf16rne(f[1 + 2*j]) | (bf16rne(f[2 + 2*j]) << 16)) & m;
          if (k == 0) pr.x = d; else pr.y = d;
        }
        *(uintx2*)(dst + 2 * jj) = pr;
      }
    }
  };

  floatx4 acc[4][4];
#pragma unroll
  for (int mt = 0; mt < 4; ++mt)
#pragma unroll
    for (int nt = 0; nt < 4; ++nt) acc[mt][nt] = 0.f;

  issue(0);
  commit(tilU[0]);
  __syncthreads();

#pragma unroll 1
  for (int c = 0; c < 5; ++c) {
    if (c < 4) issue(c + 1);
    const unsigned* buf = tilU[c & 1];
#pragma unroll
    for (int l2 = 0; l2 < 3; ++l2) {
      const int ic = c * 3 + l2;
#pragma unroll
      for (int h = 0; h < 2; ++h) {
        short8 af[4];
#pragma unroll
        for (int mt = 0; mt < 4; ++mt)
          af[mt] = *(const short8*)(Wg + (((ic * 2 + h) * 4 + mt) << 9) + lane * 8);
        short8 bfv[4];
#pragma unroll
        for (int nt = 0; nt < 4; ++nt) {
          int rrow = 2 * (w * 4 + nt) + 4 * h + q;
          int bd = l2 * 760 + rrow * 20 + ln;
          union { unsigned u[4]; short8 s; } cv;
          cv.u[0] = buf[bd]; cv.u[1] = buf[bd + 1];
          cv.u[2] = buf[bd + 2]; cv.u[3] = buf[bd + 3];
          bfv[nt] = cv.s;
        }
#pragma unroll
        for (int mt = 0; mt < 4; ++mt)
#pragma unroll
          for (int nt = 0; nt < 4; ++nt)
            acc[mt][nt] = __builtin_amdgcn_mfma_f32_16x16x32_bf16(af[mt], bfv[nt], acc[mt][nt], 0, 0, 0);
      }
    }
    if (c < 4) commit(tilU[(c + 1) & 1]);
    __syncthreads();
  }

#pragma unroll
  for (int nt = 0; nt < 4; ++nt) {
    int py = py0 + w * 4 + nt, px = px0 + ln;
    size_t rowo = (((size_t)b * GW + py) * GW + px) * 64;
#pragma unroll
    for (int mt = 0; mt < 4; ++mt) {
      int ocb = mt * 16 + q * 4;
      float v0 = fmaxf(acc[mt][nt][0] + gsh[ocb + 0], 0.f);
      float v1 = fmaxf(acc[mt][nt][1] + gsh[ocb + 1], 0.f);
      float v2 = fmaxf(acc[mt][nt][2] + gsh[ocb + 2], 0.f);
      float v3 = fmaxf(acc[mt][nt][3] + gsh[ocb + 3], 0.f);
      uintx2 pr;
      pr.x = (bf16rne(v1) << 16) | bf16rne(v0);
      pr.y = (bf16rne(v3) << 16) | bf16rne(v2);
      *(uintx2*)(Cbuf + rowo + ocb) = pr;
    }
  }
}

// ---------------- pool(3x3 s2 p1) + mean partial (full batch) ----------------
__global__ __launch_bounds__(256) void k_pool(const unsigned short* __restrict__ Cb,
                                              float* __restrict__ feat)
{
  const int py = blockIdx.x, b = blockIdx.y;
  const int t = threadIdx.x, oc = t & 63, strip = t >> 6;
  const unsigned short* base = Cb + (size_t)b * GW * GW * 64 + oc;
  float sum = 0.f;
  for (int px = strip * 24; px < strip * 24 + 24; ++px) {
    float m = 0.f;
#pragma unroll
    for (int dy = 0; dy < 3; ++dy) {
      int row = 2 * py - 1 + dy;
      if (row < 0 || row >= GW) continue;
#pragma unroll
      for (int dx = 0; dx < 3; ++dx) {
        int col = 2 * px - 1 + dx;
        if (col < 0 || col >= GW) continue;
        m = fmaxf(m, bf2f(base[((size_t)row * GW + col) * 64]));
      }
    }
    sum += m;
  }
  __shared__ float red[4][64];
  red[strip][oc] = sum;
  __syncthreads();
  if (t < 64) {
    float s = red[0][oc] + red[1][oc] + red[2][oc] + red[3][oc];
    atomicAdd(&feat[b * 64 + oc], s);
  }
}

// ---------------- FC + argmax + aux (feat holds SUMS) ----------------
__global__ __launch_bounds__(64) void k_gate_fc(
    const float* __restrict__ feat, const float* __restrict__ fcw,
    const float* __restrict__ fcb, int* __restrict__ idxb,
    float* __restrict__ out_aux)
{
  __shared__ float sm[16][3];
  __shared__ int sidx[16];
  int t = threadIdx.x;
  if (t < 16) {
    float l[3];
#pragma unroll
    for (int e = 0; e < 3; ++e) {
      float s = fcb[e];
      for (int c = 0; c < 64; ++c)
        s = fmaf(feat[t * 64 + c] * (1.f / 9216.f), fcw[e * 64 + c], s);
      l[e] = s;
    }
    int best = 0; float bv = l[0];
    if (l[1] > bv) { bv = l[1]; best = 1; }
    if (l[2] > bv) { bv = l[2]; best = 2; }
    sidx[t] = best; idxb[t] = best;
    float mx = fmaxf(l[0], fmaxf(l[1], l[2]));
    float e0 = expf(l[0] - mx), e1 = expf(l[1] - mx), e2 = expf(l[2] - mx);
    float d = e0 + e1 + e2;
    sm[t][0] = e0 / d; sm[t][1] = e1 / d; sm[t][2] = e2 / d;
  }
  __syncthreads();
  if (t == 0) {
    float aux = 0.f;
    for (int e = 0; e < 3; ++e) {
      float cnt = 0.f, pr = 0.f;
      for (int b = 0; b < 16; ++b) { cnt += (sidx[b] == e) ? 1.f : 0.f; pr += sm[b][e]; }
      aux += (cnt / 16.f) * (pr / 16.f);
    }
    *out_aux = 0.01f * aux * 3.f;
  }
}

// ---------------- zero only the Y1 halo ring (replaces 75.5 MB memset) ----------------
// NOTE: 768 is NOT a power of two — decompose with division, not & 767 (round-5 bug).
__global__ __launch_bounds__(256) void k_zring(unsigned short* __restrict__ Y1)
{
  const int b = blockIdx.x, t = threadIdx.x;
  uintx4* Yv = (uintx4*)Y1;
  uintx4 z = 0;
  for (int i = t; i < 3104; i += 256) {
    int v;
    if (i < 784) {
      v = (b * YP + 0) * 784 + i;
    } else if (i < 1568) {
      v = (b * YP + 97) * 784 + (i - 784);
    } else {
      int j = i - 1568;            // 0..1535
      int colg = j / 768;          // 0 -> col 0, 1 -> col 97
      int jj = j - colg * 768;     // 0..767
      int col = colg ? 97 : 0;
      int rr = 1 + (jj >> 3);      // rows 1..96
      v = (b * YP + rr) * 784 + col * 8 + (jj & 7);
    }
    Yv[v] = z;
  }
}

// ---------------- K4: expert conv1 7x7 s4 — LDS-staged x (round-9 + phantom fix) ----
// grid (6,12,16) block 256 (4 waves). Input patch 35 rows x 67 cols per 3-ic chunk,
// staged as TRUNCATED bf16 pairs (same v_perm as the old inline build). LDS
// [2][106][35] dw = 29,680 B. Row 105 = PHANTOM (ky=7 reads, af=0): must be ZEROED
// once — round-9 left it uninitialized, and 0 x NaN-garbage = NaN on graph replay.
__global__ __launch_bounds__(256, 3) void k_econv(
    const float* __restrict__ x, const unsigned short* __restrict__ We1,
    const float* __restrict__ biasp, const int* __restrict__ idxb,
    unsigned short* __restrict__ Y1)
{
  const int t = threadIdx.x, w = t >> 6, lane = t & 63, q = lane >> 4, ln = lane & 15;
  const int b = blockIdx.z;
  const int e = idxb[b];
  const unsigned short* W = We1 + e * 61440;
  const float* bs = biasp + e * 64;
  const int px0 = blockIdx.x * 16, py0 = blockIdx.y * 8;
  const int px = px0 + ln;
  const bool edge = (blockIdx.x == 0) | (blockIdx.y == 0);
  const bool lmask = (blockIdx.x == 0);

  __shared__ unsigned xt[2][3710];   // [2][106][35] dw; row 105 = phantom (zeroed once)

  // staging task: t < 210 -> (icl 0..2, row 0..34, half 0..1)
  const bool act = (t < 210);
  const int icl = act ? (t / 70) : 0;
  const int r2 = t - icl * 70;
  const int srow = (r2 >> 1) % 35, half = r2 & 1;
  const int iy = 4 * py0 - 3 + srow;                 // in [-3, 383]
  const int colbase = half ? (4 * px0 + 32) : (4 * px0 - 4);   // 16B-aligned
  const int abase = b * CIN * XPL + iy * HW + colbase;
  const int dloc = (icl * 35 + srow) * 35 + (half ? 18 : 0);

  // zero the phantom row (dwords 3675..3709) of BOTH buffers — never overwritten
  if (t < 35) { xt[0][3675 + t] = 0u; xt[1][3675 + t] = 0u; }

  floatx4 F[10];

  auto issue = [&](int c) {
    if (!act) return;
    int a = abase + (c * 3 + icl) * XPL;
    if (!edge) {
      const float* src = x + a;
      if (!half) {
#pragma unroll
        for (int s = 0; s < 10; ++s) F[s] = *(const floatx4*)(src + 4 * s);
      } else {
#pragma unroll
        for (int s = 0; s < 8; ++s) F[s] = *(const floatx4*)(src + 4 * s);
      }
    } else {
      const int n = half ? 8 : 10;
#pragma unroll
      for (int s = 0; s < 10; ++s) {
        if (s < n) {
          int as = a + 4 * s;
          as = max(as, 0); as = min(as, NX - 4);     // preserves 16B alignment
          F[s] = *(const floatx4*)(x + as);
        }
      }
    }
  };

  auto commit = [&](unsigned* buf) {
    if (!act) return;
    unsigned* dst = buf + dloc;
    if (iy < 0) {                                    // top halo rows (by==0 only)
      if (!half) {
#pragma unroll
        for (int k = 0; k < 18; ++k) dst[k] = 0;
      } else {
#pragma unroll
        for (int k = 0; k < 16; ++k) dst[k] = 0;
      }
      return;
    }
    if (!half) {
      // f[i] = col 4*px0-4+i ; dword k = pack(trunc(f[1+2k]), trunc(f[2+2k]))
#pragma unroll
      for (int k = 0; k < 18; ++k) {
        unsigned lo = __float_as_uint(F[(1 + 2 * k) >> 2][(1 + 2 * k) & 3]);
        unsigned hi = __float_as_uint(F[(2 + 2 * k) >> 2][(2 + 2 * k) & 3]);
        unsigned u = __builtin_amdgcn_perm(hi, lo, 0x07060302u);
        if (lmask) {                                 // cols -3,-2 (k=0); -1 (k=1 lo)
          if (k == 0) u = 0u;
          else if (k == 1) u &= 0xFFFF0000u;
        }
        dst[k] = u;
      }
    } else {
      // dword (18+k) = pack(trunc(f[1+2k]), trunc(f[2+2k])); k=15 hi = col 4*px0+64,
      // the kx=7 slot for px0+15 (weight 0) -> safe to zero (also the bx=5 phantom)
#pragma unroll
      for (int k = 0; k < 16; ++k) {
        unsigned lo = __float_as_uint(F[(1 + 2 * k) >> 2][(1 + 2 * k) & 3]);
        unsigned hi = (k == 15) ? 0u
                                : __float_as_uint(F[(2 + 2 * k) >> 2][(2 + 2 * k) & 3]);
        dst[k] = __builtin_amdgcn_perm(hi, lo, 0x07060302u);
      }
    }
  };

  floatx4 acc[4][2];
#pragma unroll
  for (int mt = 0; mt < 4; ++mt)
#pragma unroll
    for (int nt = 0; nt < 2; ++nt) acc[mt][nt] = 0.f;

  issue(0);
  commit(xt[0]);
  __syncthreads();

#pragma unroll 1
  for (int c = 0; c < 5; ++c) {
    if (c < 4) issue(c + 1);
    const unsigned* buf = xt[c & 1];
#pragma unroll
    for (int l2 = 0; l2 < 3; ++l2) {
      const int ic = c * 3 + l2;
#pragma unroll
      for (int h = 0; h < 2; ++h) {
        short8 af[4];
#pragma unroll
        for (int mt = 0; mt < 4; ++mt)
          af[mt] = *(const short8*)(W + (((ic * 2 + h) * 4 + mt) << 9) + lane * 8);
        short8 bf[2];
#pragma unroll
        for (int nt = 0; nt < 2; ++nt) {
          int lr = 4 * (2 * w + nt) + 4 * h + q;     // 35 = phantom row (zeroed)
          int bd = (l2 * 35 + lr) * 35 + 2 * ln;
          union { unsigned u[4]; short8 s; } cv;
          cv.u[0] = buf[bd]; cv.u[1] = buf[bd + 1];
          cv.u[2] = buf[bd + 2]; cv.u[3] = buf[bd + 3];
          bf[nt] = cv.s;
        }
#pragma unroll
        for (int mt = 0; mt < 4; ++mt)
#pragma unroll
          for (int nt = 0; nt < 2; ++nt)
            acc[mt][nt] = __builtin_amdgcn_mfma_f32_16x16x32_bf16(af[mt], bf[nt], acc[mt][nt], 0, 0, 0);
      }
    }
    if (c < 4) commit(xt[(c + 1) & 1]);
    __syncthreads();
  }

#pragma unroll
  for (int nt = 0; nt < 2; ++nt) {
    int py = py0 + w * 2 + nt;
    size_t rowo = (((size_t)b * YP + py + 1) * YP + px + 1) * 64;
#pragma unroll
    for (int mt = 0; mt < 4; ++mt) {
      int ocb = mt * 16 + q * 4;
      float v0 = fmaxf(acc[mt][nt][0] + bs[ocb + 0], 0.f);
      float v1 = fmaxf(acc[mt][nt][1] + bs[ocb + 1], 0.f);
      float v2 = fmaxf(acc[mt][nt][2] + bs[ocb + 2], 0.f);
      float v3 = fmaxf(acc[mt][nt][3] + bs[ocb + 3], 0.f);
      uintx2 pr;
      pr.x = (bf16rne(v1) << 16) | bf16rne(v0);
      pr.y = (bf16rne(v3) << 16) | bf16rne(v2);
      *(uintx2*)(Y1 + rowo + ocb) = pr;
    }
  }
}

// ---------------- head: 3x3 64->384 MFMA — 12-wave blocks, acc[6][2] per wave ----------
__global__ __launch_bounds__(768, 3) void k_headm(
    const unsigned short* __restrict__ Y1, const unsigned short* __restrict__ Whp,
    const float* __restrict__ b1, const float* __restrict__ w2,
    const float* __restrict__ b2, const int* __restrict__ idxb,
    float* __restrict__ out)
{
  const int t = threadIdx.x, w = t >> 6, lane = t & 63, q = lane >> 4, ln = lane & 15;
  const int wo = w & 3, wn = w >> 2;           // oc-group 0..3, py-pair 0..2
  const int b = blockIdx.z, px0 = blockIdx.x * 16, py0 = blockIdx.y * 6;
  const int e = idxb[b];
  const unsigned short* W = Whp + e * 221184;

  __shared__ unsigned short patch[8 * 18 * 72];   // 20,736 B; rows py0-1..+6, cols px0-1..+16
  __shared__ float sred[6][4][16][6];             // 9,216 B

  // stage 8*18*8 = 1152 b128 segs, batched over 768 threads (2 in flight)
  {
    uintx4 vv[2];
#pragma unroll
    for (int r = 0; r < 2; ++r) {
      int i = r * 768 + t;
      if (i < 1152) {
        int row = i / 144, rem = i % 144, col = rem >> 3, s = rem & 7;
        vv[r] = *(const uintx4*)(Y1 + (((size_t)b * YP + py0 + row) * YP + (px0 + col)) * 64 + s * 8);
      }
    }
#pragma unroll
    for (int r = 0; r < 2; ++r) {
      int i = r * 768 + t;
      if (i < 1152) {
        int row = i / 144, rem = i % 144, col = rem >> 3, s = rem & 7;
        *(uintx4*)(patch + (row * 18 + col) * 72 + s * 8) = vv[r];
      }
    }
  }
  __syncthreads();

  floatx4 acc[6][2];
#pragma unroll
  for (int mt = 0; mt < 6; ++mt)
#pragma unroll
    for (int j = 0; j < 2; ++j) acc[mt][j] = 0.f;

#pragma unroll
  for (int kk = 0; kk < 9; ++kk) {
    const int ky = kk / 3, kx = kk % 3;
#pragma unroll
    for (int ih = 0; ih < 2; ++ih) {
      short8 bf[2];
#pragma unroll
      for (int j = 0; j < 2; ++j) {
        int nt = wn * 2 + j;
        int off = ((nt + ky) * 18 + (ln + kx)) * 72 + ih * 32 + q * 8;
        bf[j] = *(const short8*)(patch + off);
      }
      const int cbase = ((kk * 2 + ih) * 24 + wo * 6) << 9;
#pragma unroll
      for (int mt = 0; mt < 6; ++mt) {
        short8 af = *(const short8*)(W + cbase + (mt << 9) + lane * 8);
#pragma unroll
        for (int j = 0; j < 2; ++j)
          acc[mt][j] = __builtin_amdgcn_mfma_f32_16x16x32_bf16(af, bf[j], acc[mt][j], 0, 0, 0);
      }
    }
  }

#pragma unroll
  for (int j = 0; j < 2; ++j) {
    const int nt = wn * 2 + j;
    float part[6] = {0.f, 0.f, 0.f, 0.f, 0.f, 0.f};
#pragma unroll
    for (int mt = 0; mt < 6; ++mt) {
      int ocb = wo * 96 + mt * 16 + q * 4;
#pragma unroll
      for (int r = 0; r < 4; ++r) {
        int oc = ocb + r;
        float y = fmaxf(acc[mt][j][r] + b1[e * 384 + oc], 0.f);
        int g = oc >> 7, kb = oc & 127;
        part[2 * g]     += y * w2[(e * 6 + 2 * g) * 128 + kb];
        part[2 * g + 1] += y * w2[(e * 6 + 2 * g + 1) * 128 + kb];
      }
    }
#pragma unroll
    for (int c = 0; c < 6; ++c) {
      part[c] += __shfl_down(part[c], 32);
      part[c] += __shfl_down(part[c], 16);
    }
    if (q == 0) {
#pragma unroll
      for (int c = 0; c < 6; ++c) sred[nt][wo][ln][c] = part[c];
    }
  }
  __syncthreads();
  if (t < 576) {
    int pix = t / 6, c = t % 6;
    int nt = pix >> 4, pl = pix & 15;
    float s = sred[nt][0][pl][c] + sred[nt][1][pl][c] + sred[nt][2][pl][c] +
              sred[nt][3][pl][c] + b2[e * 6 + c];
    out[(((size_t)(b * 6 + c)) * PH + (py0 + nt)) * PH + (px0 + pl)] = s;
  }
}

// ---------------- launch ----------------
extern "C" void kernel_launch(void* const* d_in, const int* in_sizes, int n_in,
                              void* d_out, int out_size, void* d_ws, size_t ws_size,
                              hipStream_t stream)
{
  const float* x         = (const float*)d_in[0];
  const float* g_fc_w    = (const float*)d_in[6];
  const float* g_fc_b    = (const float*)d_in[7];
  const float* e_conv1_b = (const float*)d_in[9];
  const float* e_head_b1 = (const float*)d_in[11];
  const float* e_head_w2 = (const float*)d_in[12];
  const float* e_head_b2 = (const float*)d_in[13];

  unsigned char* wsb = (unsigned char*)d_ws;
  unsigned short* Wg  = (unsigned short*)(wsb + OFF_WG);
  unsigned short* We1 = (unsigned short*)(wsb + OFF_WE1);
  unsigned short* Wh  = (unsigned short*)(wsb + OFF_WH);
  float* gsh  = (float*)(wsb + OFF_GSH);
  float* feat = (float*)(wsb + OFF_FEAT);
  int*   idxb = (int*)(wsb + OFF_IDX);
  unsigned short* Cbuf = (unsigned short*)(wsb + OFF_CBUF);
  unsigned short* Y1   = (unsigned short*)(wsb + OFF_CBUF);  // overlays Cbuf

  float* out = (float*)d_out;
  float* out_aux = out + OUT_ELEMS;

  hipMemsetAsync(feat, 0, 16 * 64 * sizeof(float), stream);
  hipLaunchKernelGGL(k_prep, dim3(3553), dim3(256), 0, stream,
                     (const float*)d_in[1], (const float*)d_in[8], (const float*)d_in[10],
                     (const float*)d_in[2], (const float*)d_in[5],
                     (const float*)d_in[3], (const float*)d_in[4], wsb);

  hipLaunchKernelGGL(k_gconv, dim3(12, 12, 16), dim3(256), 0, stream,
                     x, Wg, gsh, Cbuf);
  hipLaunchKernelGGL(k_pool, dim3(96, 16), dim3(256), 0, stream, Cbuf, feat);
  hipLaunchKernelGGL(k_gate_fc, dim3(1), dim3(64), 0, stream,
                     feat, g_fc_w, g_fc_b, idxb, out_aux);

  // Y1 overlays Cbuf (consumed by pool); zero only the halo ring, econv fills interior
  hipLaunchKernelGGL(k_zring, dim3(16), dim3(256), 0, stream, Y1);
  hipLaunchKernelGGL(k_econv, dim3(6, 12, 16), dim3(256), 0, stream,
                     x, We1, e_conv1_b, idxb, Y1);

  hipLaunchKernelGGL(k_headm, dim3(6, 16, 16), dim3(768), 0, stream,
                     Y1, Wh, e_head_b1, e_head_w2, e_head_b2, idxb, out);
}

// Round 11
// 545.935 us; speedup vs baseline: 1.0972x; 1.0972x over previous
//
#include <hip/hip_runtime.h>
#include <math.h>

// ---------------- problem constants ----------------
#define BB 16
#define CIN 15
#define HW 384
#define XPL 147456             // 384*384
#define NX 35389440            // 16*15*384*384
#define PH 96
#define GW 192
#define YP 98                  // padded Y1 spatial
#define Y1IPL (98*98*64)       // 614656 elems per image
#define OUT_ELEMS (BB*6*PH*PH)

// ws byte offsets (end = 77,594,624 == proven available, round-4 layout)
#define OFF_WG   0             // frag-major [30][4][512] bf16 (BN-folded)
#define OFF_WE1  122880        // frag-major [3][30][4][512] bf16
#define OFF_WH   491520        // frag-major [3][18][24][512] bf16
#define OFF_GSH  1818624       // fp32 [64]
#define OFF_FEAT 1818880       // fp32 [16][64]
#define OFF_IDX  1822976       // int  [16]
#define OFF_CBUF 2097152       // bf16 [16][192][192][64] = 75,497,472 B; Y1 overlays

typedef __attribute__((ext_vector_type(8))) short short8;
typedef __attribute__((ext_vector_type(4))) float floatx4;
typedef __attribute__((ext_vector_type(4))) unsigned int uintx4;
typedef __attribute__((ext_vector_type(2))) unsigned int uintx2;

__device__ __forceinline__ unsigned bf16rne(float f) {
  unsigned u = __float_as_uint(f);
  unsigned r = ((u >> 16) & 1u) + 0x7FFFu;
  return (u + r) >> 16;
}
__device__ __forceinline__ float bf2f(unsigned short s) {
  return __uint_as_float(((unsigned)s) << 16);
}

// ---------------- K0: weight prep (fragment-major) — round-4 verbatim ----------------
__global__ __launch_bounds__(256) void k_prep(
    const float* __restrict__ g_conv_w, const float* __restrict__ e_conv1_w,
    const float* __restrict__ e_head_w1,
    const float* __restrict__ gamma, const float* __restrict__ var,
    const float* __restrict__ beta,  const float* __restrict__ mean,
    unsigned char* __restrict__ wsb)
{
  int i = blockIdx.x * 256 + threadIdx.x;
  unsigned short* Wg  = (unsigned short*)(wsb + OFF_WG);
  unsigned short* We1 = (unsigned short*)(wsb + OFF_WE1);
  unsigned short* Wh  = (unsigned short*)(wsb + OFF_WH);
  float* gsh = (float*)(wsb + OFF_GSH);
  if (i < 61440) {
    int j = i & 7, lane = (i >> 3) & 63, mtc = i >> 9;
    int mt = mtc & 3, c = mtc >> 2, ic = c >> 1, h = c & 1;
    int oc = mt * 16 + (lane & 15), q = lane >> 4;
    int ky = 4 * h + q, kx = j;
    float v = 0.f;
    if (ky < 7 && kx < 7) v = g_conv_w[oc * 735 + ic * 49 + ky * 7 + kx];
    float inv = gamma[oc] * rsqrtf(var[oc] + 1e-5f);
    Wg[i] = (unsigned short)bf16rne(v * inv);
  } else if (i < 245760) {
    int r = i - 61440;
    int e = r / 61440, r2 = r % 61440;
    int j = r2 & 7, lane = (r2 >> 3) & 63, mtc = r2 >> 9;
    int mt = mtc & 3, c = mtc >> 2, ic = c >> 1, h = c & 1;
    int oc = mt * 16 + (lane & 15), q = lane >> 4;
    int ky = 4 * h + q, kx = j;
    float v = 0.f;
    if (ky < 7 && kx < 7) v = e_conv1_w[(e * 64 + oc) * 735 + ic * 49 + ky * 7 + kx];
    We1[r] = (unsigned short)bf16rne(v);
  } else if (i < 909312) {
    int r = i - 245760;
    int e = r / 221184, r2 = r % 221184;
    int j = r2 & 7, lane = (r2 >> 3) & 63, mtc = r2 >> 9;
    int mt = mtc % 24, chunk = mtc / 24;
    int kk = chunk >> 1, ih = chunk & 1;
    int oc = mt * 16 + (lane & 15), q = lane >> 4;
    int ic = ih * 32 + q * 8 + j;
    Wh[r] = (unsigned short)bf16rne(e_head_w1[((e * 384 + oc) * 64 + ic) * 9 + kk]);
  } else if (i < 909376) {
    int oc = i - 909312;
    float inv = gamma[oc] * rsqrtf(var[oc] + 1e-5f);
    gsh[oc] = beta[oc] - mean[oc] * inv;
  }
}

// ---------------- K1: gating conv 7x7 s2 — ic-chunked double-buffered pipeline ------
// ROUND-6 VERBATIM (164 µs). Occupancy ~10 waves/CU here PROTECTS L2 write combining
// (round-7: 512-thr raised occupancy to 58% but WRITE_SIZE 74->302MB -> 271 µs).
__global__ __launch_bounds__(256, 3) void k_gconv(
    const float* __restrict__ x, const unsigned short* __restrict__ Wg,
    const float* __restrict__ gsh, unsigned short* __restrict__ Cbuf)
{
  const int t = threadIdx.x, w = t >> 6, lane = t & 63, q = lane >> 4, ln = lane & 15;

  // XCD-aware bijective swizzle: consecutive tiles (shared halo) -> same XCD L2
  int lin = blockIdx.x + 12 * (blockIdx.y + 12 * blockIdx.z);
  int nl = (lin & 7) * 288 + (lin >> 3);
  const int b = nl / 144; int r144 = nl - b * 144;
  const int by = r144 / 12, bx = r144 - by * 12;

  const int px0 = bx * 16, py0 = by * 16;
  const int iy0 = 2 * py0 - 3, ix0 = 2 * px0 - 3;
  const bool edge = (bx == 0) | (bx == 11) | (by == 0) | (by == 11);
  const int xbase = b * CIN * XPL;

  __shared__ unsigned tilU[2][2280];   // 18,240 B

  // staging task: t < 228 -> (lic 0..2, srow 0..37, half 0..1)
  const bool act = (t < 228);
  const int lic = t / 76, r2 = t - lic * 76, srow = r2 >> 1, half = r2 & 1;
  const int iy = iy0 + srow;
  const int A = ix0 + 20 * half - 1;                 // == 0 (mod 4)
  const unsigned rowm = (iy >= 0 && iy < HW) ? 0xFFFFFFFFu : 0u;
  const int abase = xbase + iy * HW + A;
  const int dloc = (lic * 38 + srow) * 20 + 10 * half;

  floatx4 F[6];

  auto issue = [&](int c) {
    if (!act) return;
    int a = abase + (c * 3 + lic) * XPL;
    if (!edge) {
      const float* src = x + a;
#pragma unroll
      for (int s = 0; s < 6; ++s) F[s] = *(const floatx4*)(src + 4 * s);
    } else {
#pragma unroll
      for (int s = 0; s < 6; ++s) {
        int as = a + 4 * s;
        as = max(as, 0); as = min(as, NX - 4);       // preserves 16B alignment
        F[s] = *(const floatx4*)(x + as);
      }
    }
  };

  auto commit = [&](unsigned* buf) {
    if (!act) return;
    float f[24];
#pragma unroll
    for (int s = 0; s < 6; ++s) {
      f[4*s] = F[s].x; f[4*s+1] = F[s].y; f[4*s+2] = F[s].z; f[4*s+3] = F[s].w;
    }
    unsigned* dst = buf + dloc;
    if (!edge) {
#pragma unroll
      for (int jj = 0; jj < 5; ++jj) {
        uintx2 pr;
        pr.x = bf16rne(f[1 + 4*jj]) | (bf16rne(f[2 + 4*jj]) << 16);
        pr.y = bf16rne(f[3 + 4*jj]) | (bf16rne(f[4 + 4*jj]) << 16);
        *(uintx2*)(dst + 2 * jj) = pr;
      }
    } else {
#pragma unroll
      for (int jj = 0; jj < 5; ++jj) {
        uintx2 pr;
#pragma unroll
        for (int k = 0; k < 2; ++k) {
          int j = 2 * jj + k;
          int cc = A + 1 + 2 * j;
          unsigned m = rowm;
          m &= ((cc >= 0) && (cc < HW)) ? 0xFFFFFFFFu : 0xFFFF0000u;
          m &= ((cc + 1 >= 0) && (cc + 1 < HW)) ? 0xFFFFFFFFu : 0x0000FFFFu;
          unsigned d = (bf16rne(f[1 + 2*j]) | (bf16rne(f[2 + 2*j]) << 16)) & m;
          if (k == 0) pr.x = d; else pr.y = d;
        }
        *(uintx2*)(dst + 2 * jj) = pr;
      }
    }
  };

  floatx4 acc[4][4];
#pragma unroll
  for (int mt = 0; mt < 4; ++mt)
#pragma unroll
    for (int nt = 0; nt < 4; ++nt) acc[mt][nt] = 0.f;

  issue(0);
  commit(tilU[0]);
  __syncthreads();

#pragma unroll 1
  for (int c = 0; c < 5; ++c) {
    if (c < 4) issue(c + 1);
    const unsigned* buf = tilU[c & 1];
#pragma unroll
    for (int l2 = 0; l2 < 3; ++l2) {
      const int ic = c * 3 + l2;
#pragma unroll
      for (int h = 0; h < 2; ++h) {
        short8 af[4];
#pragma unroll
        for (int mt = 0; mt < 4; ++mt)
          af[mt] = *(const short8*)(Wg + (((ic * 2 + h) * 4 + mt) << 9) + lane * 8);
        short8 bfv[4];
#pragma unroll
        for (int nt = 0; nt < 4; ++nt) {
          int rrow = 2 * (w * 4 + nt) + 4 * h + q;
          int bd = l2 * 760 + rrow * 20 + ln;
          union { unsigned u[4]; short8 s; } cv;
          cv.u[0] = buf[bd]; cv.u[1] = buf[bd + 1];
          cv.u[2] = buf[bd + 2]; cv.u[3] = buf[bd + 3];
          bfv[nt] = cv.s;
        }
#pragma unroll
        for (int mt = 0; mt < 4; ++mt)
#pragma unroll
          for (int nt = 0; nt < 4; ++nt)
            acc[mt][nt] = __builtin_amdgcn_mfma_f32_16x16x32_bf16(af[mt], bfv[nt], acc[mt][nt], 0, 0, 0);
      }
    }
    if (c < 4) commit(tilU[(c + 1) & 1]);
    __syncthreads();
  }

#pragma unroll
  for (int nt = 0; nt < 4; ++nt) {
    int py = py0 + w * 4 + nt, px = px0 + ln;
    size_t rowo = (((size_t)b * GW + py) * GW + px) * 64;
#pragma unroll
    for (int mt = 0; mt < 4; ++mt) {
      int ocb = mt * 16 + q * 4;
      float v0 = fmaxf(acc[mt][nt][0] + gsh[ocb + 0], 0.f);
      float v1 = fmaxf(acc[mt][nt][1] + gsh[ocb + 1], 0.f);
      float v2 = fmaxf(acc[mt][nt][2] + gsh[ocb + 2], 0.f);
      float v3 = fmaxf(acc[mt][nt][3] + gsh[ocb + 3], 0.f);
      uintx2 pr;
      pr.x = (bf16rne(v1) << 16) | bf16rne(v0);
      pr.y = (bf16rne(v3) << 16) | bf16rne(v2);
      *(uintx2*)(Cbuf + rowo + ocb) = pr;
    }
  }
}

// ---------------- pool(3x3 s2 p1) + mean partial — VECTORIZED 4-oc loads ------------
// grid (96,16) block 256: ocq = t&15 (4 oc via one uintx2), seg = t>>4 (6 px each).
// 4x fewer load instructions than scalar version (54 vs 216 per thread), same bytes.
// Per-oc summation regrouped (segs of 6 px) — fp32-ulp noise only, argmax-safe.
__global__ __launch_bounds__(256) void k_pool(const unsigned short* __restrict__ Cb,
                                              float* __restrict__ feat)
{
  const int py = blockIdx.x, b = blockIdx.y;
  const int t = threadIdx.x, ocq = t & 15, seg = t >> 4;
  const unsigned short* base = Cb + (size_t)b * GW * GW * 64 + 4 * ocq;
  float sum[4] = {0.f, 0.f, 0.f, 0.f};
  for (int px = seg * 6; px < seg * 6 + 6; ++px) {
    float m[4] = {0.f, 0.f, 0.f, 0.f};
#pragma unroll
    for (int dy = 0; dy < 3; ++dy) {
      int row = 2 * py - 1 + dy;
      if (row < 0 || row >= GW) continue;
#pragma unroll
      for (int dx = 0; dx < 3; ++dx) {
        int col = 2 * px - 1 + dx;
        if (col < 0 || col >= GW) continue;
        uintx2 v = *(const uintx2*)(base + ((size_t)row * GW + col) * 64);
        m[0] = fmaxf(m[0], bf2f((unsigned short)(v.x & 0xFFFFu)));
        m[1] = fmaxf(m[1], bf2f((unsigned short)(v.x >> 16)));
        m[2] = fmaxf(m[2], bf2f((unsigned short)(v.y & 0xFFFFu)));
        m[3] = fmaxf(m[3], bf2f((unsigned short)(v.y >> 16)));
      }
    }
#pragma unroll
    for (int c = 0; c < 4; ++c) sum[c] += m[c];
  }
  __shared__ float sred[16][16][4];   // [seg][ocq][c]
#pragma unroll
  for (int c = 0; c < 4; ++c) sred[seg][ocq][c] = sum[c];
  __syncthreads();
  if (t < 64) {
    int oq = t >> 2, c = t & 3;
    float s = 0.f;
#pragma unroll
    for (int sg = 0; sg < 16; ++sg) s += sred[sg][oq][c];
    atomicAdd(&feat[b * 64 + 4 * oq + c], s);
  }
}

// ---------------- FC + argmax + aux (feat holds SUMS) ----------------
__global__ __launch_bounds__(64) void k_gate_fc(
    const float* __restrict__ feat, const float* __restrict__ fcw,
    const float* __restrict__ fcb, int* __restrict__ idxb,
    float* __restrict__ out_aux)
{
  __shared__ float sm[16][3];
  __shared__ int sidx[16];
  int t = threadIdx.x;
  if (t < 16) {
    float l[3];
#pragma unroll
    for (int e = 0; e < 3; ++e) {
      float s = fcb[e];
      for (int c = 0; c < 64; ++c)
        s = fmaf(feat[t * 64 + c] * (1.f / 9216.f), fcw[e * 64 + c], s);
      l[e] = s;
    }
    int best = 0; float bv = l[0];
    if (l[1] > bv) { bv = l[1]; best = 1; }
    if (l[2] > bv) { bv = l[2]; best = 2; }
    sidx[t] = best; idxb[t] = best;
    float mx = fmaxf(l[0], fmaxf(l[1], l[2]));
    float e0 = expf(l[0] - mx), e1 = expf(l[1] - mx), e2 = expf(l[2] - mx);
    float d = e0 + e1 + e2;
    sm[t][0] = e0 / d; sm[t][1] = e1 / d; sm[t][2] = e2 / d;
  }
  __syncthreads();
  if (t == 0) {
    float aux = 0.f;
    for (int e = 0; e < 3; ++e) {
      float cnt = 0.f, pr = 0.f;
      for (int b = 0; b < 16; ++b) { cnt += (sidx[b] == e) ? 1.f : 0.f; pr += sm[b][e]; }
      aux += (cnt / 16.f) * (pr / 16.f);
    }
    *out_aux = 0.01f * aux * 3.f;
  }
}

// ---------------- K4: expert conv1 7x7 s4 — round-8 verbatim + fused ring-zero ------
// grid (6,12,16) = 1152 blocks. Wave w handles rows 2w, 2w+1 -> acc[4][2].
// Prologue: each block zeroes a 44-vec16 slice of its image's Y1 halo ring (replaces
// k_zring launch). Ring (rows 0/97, cols 0/97) is disjoint from econv's interior
// writes (rows/cols 1..96); headm launches after econv completes -> ordering safe.
// NOTE: 768 is NOT a power of two — decompose with division, not & 767 (round-5 bug).
__global__ __launch_bounds__(256, 4) void k_econv(
    const float* __restrict__ x, const unsigned short* __restrict__ We1,
    const float* __restrict__ biasp, const int* __restrict__ idxb,
    unsigned short* __restrict__ Y1)
{
  const int t = threadIdx.x, w = t >> 6, lane = t & 63, q = lane >> 4, ln = lane & 15;
  const int b = blockIdx.z;

  // ---- fused Y1 halo-ring zero (slice k of 72 per image; 72*44 >= 3104) ----
  {
    int k = blockIdx.x + 6 * blockIdx.y;             // 0..71
    int i = k * 44 + t;
    if (t < 44 && i < 3104) {
      int v;
      if (i < 784) {
        v = (b * YP + 0) * 784 + i;
      } else if (i < 1568) {
        v = (b * YP + 97) * 784 + (i - 784);
      } else {
        int j = i - 1568;            // 0..1535
        int colg = j / 768;          // 0 -> col 0, 1 -> col 97
        int jj = j - colg * 768;     // 0..767
        int col = colg ? 97 : 0;
        int rr = 1 + (jj >> 3);      // rows 1..96
        v = (b * YP + rr) * 784 + col * 8 + (jj & 7);
      }
      uintx4 z = 0;
      ((uintx4*)Y1)[v] = z;
    }
  }

  const int e = idxb[b];
  const unsigned short* W = We1 + e * 61440;
  const float* bs = biasp + e * 64;
  const int px0 = blockIdx.x * 16, py0 = blockIdx.y * 8;
  const int px = px0 + ln;

  const int c0 = 4 * px - 3;
  const int acol = c0 - 1;
  unsigned pm[4];
#pragma unroll
  for (int j = 0; j < 4; ++j) {
    int t0 = 2 * j, t1 = 2 * j + 1;
    unsigned m0 = (c0 + t0 >= 0 && c0 + t0 < HW) ? 0x0000FFFFu : 0u;
    unsigned m1 = (c0 + t1 >= 0 && c0 + t1 < HW) ? 0xFFFF0000u : 0u;
    pm[j] = m0 | m1;
  }

  int syq[2];
#pragma unroll
  for (int nt = 0; nt < 2; ++nt) syq[nt] = 4 * (py0 + w * 2 + nt) + q - 3;
  const int xbase = b * CIN * XPL;

  floatx4 acc[4][2];
#pragma unroll
  for (int mt = 0; mt < 4; ++mt)
#pragma unroll
    for (int nt = 0; nt < 2; ++nt) acc[mt][nt] = 0.f;

#pragma unroll 3
  for (int ic = 0; ic < CIN; ++ic) {
    const int icb = xbase + ic * XPL;
#pragma unroll
    for (int h = 0; h < 2; ++h) {
      short8 af[4];
#pragma unroll
      for (int mt = 0; mt < 4; ++mt)
        af[mt] = *(const short8*)(W + (((ic * 2 + h) * 4 + mt) << 9) + lane * 8);
      short8 bf[2];
#pragma unroll
      for (int nt = 0; nt < 2; ++nt) {
        int iy = syq[nt] + 4 * h;
        bool rv = (iy >= 0) && (iy < HW) && ((4 * h + q) < 7);
        int a0 = icb + iy * HW + acol;
        a0 = max(a0, 0); a0 = min(a0, NX - 12);
        const float* fp = x + a0;
        floatx4 fA = *(const floatx4*)(fp);
        floatx4 fB = *(const floatx4*)(fp + 4);
        floatx4 fC = *(const floatx4*)(fp + 8);
        float g[8];
        g[0] = fA.y; g[1] = fA.z; g[2] = fA.w; g[3] = fB.x;
        g[4] = fB.y; g[5] = fB.z; g[6] = fB.w; g[7] = fC.x;
        union { unsigned u[4]; short8 s; } cv;
#pragma unroll
        for (int j = 0; j < 4; ++j) {
          unsigned p = __builtin_amdgcn_perm(__float_as_uint(g[2 * j + 1]),
                                             __float_as_uint(g[2 * j]), 0x07060302u);
          p &= pm[j];
          cv.u[j] = rv ? p : 0u;
        }
        bf[nt] = cv.s;
      }
#pragma unroll
      for (int mt = 0; mt < 4; ++mt)
#pragma unroll
        for (int nt = 0; nt < 2; ++nt)
          acc[mt][nt] = __builtin_amdgcn_mfma_f32_16x16x32_bf16(af[mt], bf[nt], acc[mt][nt], 0, 0, 0);
    }
  }

#pragma unroll
  for (int nt = 0; nt < 2; ++nt) {
    int py = py0 + w * 2 + nt;
    size_t rowo = (((size_t)b * YP + py + 1) * YP + px + 1) * 64;
#pragma unroll
    for (int mt = 0; mt < 4; ++mt) {
      int ocb = mt * 16 + q * 4;
      float v0 = fmaxf(acc[mt][nt][0] + bs[ocb + 0], 0.f);
      float v1 = fmaxf(acc[mt][nt][1] + bs[ocb + 1], 0.f);
      float v2 = fmaxf(acc[mt][nt][2] + bs[ocb + 2], 0.f);
      float v3 = fmaxf(acc[mt][nt][3] + bs[ocb + 3], 0.f);
      uintx2 pr;
      pr.x = (bf16rne(v1) << 16) | bf16rne(v0);
      pr.y = (bf16rne(v3) << 16) | bf16rne(v2);
      *(uintx2*)(Y1 + rowo + ocb) = pr;
    }
  }
}

// ---------------- head: 3x3 64->384 MFMA — 12-wave blocks, acc[6][2] per wave ----------
__global__ __launch_bounds__(768, 3) void k_headm(
    const unsigned short* __restrict__ Y1, const unsigned short* __restrict__ Whp,
    const float* __restrict__ b1, const float* __restrict__ w2,
    const float* __restrict__ b2, const int* __restrict__ idxb,
    float* __restrict__ out)
{
  const int t = threadIdx.x, w = t >> 6, lane = t & 63, q = lane >> 4, ln = lane & 15;
  const int wo = w & 3, wn = w >> 2;           // oc-group 0..3, py-pair 0..2
  const int b = blockIdx.z, px0 = blockIdx.x * 16, py0 = blockIdx.y * 6;
  const int e = idxb[b];
  const unsigned short* W = Whp + e * 221184;

  __shared__ unsigned short patch[8 * 18 * 72];   // 20,736 B; rows py0-1..+6, cols px0-1..+16
  __shared__ float sred[6][4][16][6];             // 9,216 B

  // stage 8*18*8 = 1152 b128 segs, batched over 768 threads (2 in flight)
  {
    uintx4 vv[2];
#pragma unroll
    for (int r = 0; r < 2; ++r) {
      int i = r * 768 + t;
      if (i < 1152) {
        int row = i / 144, rem = i % 144, col = rem >> 3, s = rem & 7;
        vv[r] = *(const uintx4*)(Y1 + (((size_t)b * YP + py0 + row) * YP + (px0 + col)) * 64 + s * 8);
      }
    }
#pragma unroll
    for (int r = 0; r < 2; ++r) {
      int i = r * 768 + t;
      if (i < 1152) {
        int row = i / 144, rem = i % 144, col = rem >> 3, s = rem & 7;
        *(uintx4*)(patch + (row * 18 + col) * 72 + s * 8) = vv[r];
      }
    }
  }
  __syncthreads();

  floatx4 acc[6][2];
#pragma unroll
  for (int mt = 0; mt < 6; ++mt)
#pragma unroll
    for (int j = 0; j < 2; ++j) acc[mt][j] = 0.f;

#pragma unroll
  for (int kk = 0; kk < 9; ++kk) {
    const int ky = kk / 3, kx = kk % 3;
#pragma unroll
    for (int ih = 0; ih < 2; ++ih) {
      short8 bf[2];
#pragma unroll
      for (int j = 0; j < 2; ++j) {
        int nt = wn * 2 + j;
        int off = ((nt + ky) * 18 + (ln + kx)) * 72 + ih * 32 + q * 8;
        bf[j] = *(const short8*)(patch + off);
      }
      const int cbase = ((kk * 2 + ih) * 24 + wo * 6) << 9;
#pragma unroll
      for (int mt = 0; mt < 6; ++mt) {
        short8 af = *(const short8*)(W + cbase + (mt << 9) + lane * 8);
#pragma unroll
        for (int j = 0; j < 2; ++j)
          acc[mt][j] = __builtin_amdgcn_mfma_f32_16x16x32_bf16(af, bf[j], acc[mt][j], 0, 0, 0);
      }
    }
  }

#pragma unroll
  for (int j = 0; j < 2; ++j) {
    const int nt = wn * 2 + j;
    float part[6] = {0.f, 0.f, 0.f, 0.f, 0.f, 0.f};
#pragma unroll
    for (int mt = 0; mt < 6; ++mt) {
      int ocb = wo * 96 + mt * 16 + q * 4;
#pragma unroll
      for (int r = 0; r < 4; ++r) {
        int oc = ocb + r;
        float y = fmaxf(acc[mt][j][r] + b1[e * 384 + oc], 0.f);
        int g = oc >> 7, kb = oc & 127;
        part[2 * g]     += y * w2[(e * 6 + 2 * g) * 128 + kb];
        part[2 * g + 1] += y * w2[(e * 6 + 2 * g + 1) * 128 + kb];
      }
    }
#pragma unroll
    for (int c = 0; c < 6; ++c) {
      part[c] += __shfl_down(part[c], 32);
      part[c] += __shfl_down(part[c], 16);
    }
    if (q == 0) {
#pragma unroll
      for (int c = 0; c < 6; ++c) sred[nt][wo][ln][c] = part[c];
    }
  }
  __syncthreads();
  if (t < 576) {
    int pix = t / 6, c = t % 6;
    int nt = pix >> 4, pl = pix & 15;
    float s = sred[nt][0][pl][c] + sred[nt][1][pl][c] + sred[nt][2][pl][c] +
              sred[nt][3][pl][c] + b2[e * 6 + c];
    out[(((size_t)(b * 6 + c)) * PH + (py0 + nt)) * PH + (px0 + pl)] = s;
  }
}

// ---------------- launch ----------------
extern "C" void kernel_launch(void* const* d_in, const int* in_sizes, int n_in,
                              void* d_out, int out_size, void* d_ws, size_t ws_size,
                              hipStream_t stream)
{
  const float* x         = (const float*)d_in[0];
  const float* g_fc_w    = (const float*)d_in[6];
  const float* g_fc_b    = (const float*)d_in[7];
  const float* e_conv1_b = (const float*)d_in[9];
  const float* e_head_b1 = (const float*)d_in[11];
  const float* e_head_w2 = (const float*)d_in[12];
  const float* e_head_b2 = (const float*)d_in[13];

  unsigned char* wsb = (unsigned char*)d_ws;
  unsigned short* Wg  = (unsigned short*)(wsb + OFF_WG);
  unsigned short* We1 = (unsigned short*)(wsb + OFF_WE1);
  unsigned short* Wh  = (unsigned short*)(wsb + OFF_WH);
  float* gsh  = (float*)(wsb + OFF_GSH);
  float* feat = (float*)(wsb + OFF_FEAT);
  int*   idxb = (int*)(wsb + OFF_IDX);
  unsigned short* Cbuf = (unsigned short*)(wsb + OFF_CBUF);
  unsigned short* Y1   = (unsigned short*)(wsb + OFF_CBUF);  // overlays Cbuf

  float* out = (float*)d_out;
  float* out_aux = out + OUT_ELEMS;

  hipMemsetAsync(feat, 0, 16 * 64 * sizeof(float), stream);
  hipLaunchKernelGGL(k_prep, dim3(3553), dim3(256), 0, stream,
                     (const float*)d_in[1], (const float*)d_in[8], (const float*)d_in[10],
                     (const float*)d_in[2], (const float*)d_in[5],
                     (const float*)d_in[3], (const float*)d_in[4], wsb);

  hipLaunchKernelGGL(k_gconv, dim3(12, 12, 16), dim3(256), 0, stream,
                     x, Wg, gsh, Cbuf);
  hipLaunchKernelGGL(k_pool, dim3(96, 16), dim3(256), 0, stream, Cbuf, feat);
  hipLaunchKernelGGL(k_gate_fc, dim3(1), dim3(64), 0, stream,
                     feat, g_fc_w, g_fc_b, idxb, out_aux);

  // Y1 overlays Cbuf (consumed by pool); econv zeroes the halo ring in its prologue
  hipLaunchKernelGGL(k_econv, dim3(6, 12, 16), dim3(256), 0, stream,
                     x, We1, e_conv1_b, idxb, Y1);

  hipLaunchKernelGGL(k_headm, dim3(6, 16, 16), dim3(768), 0, stream,
                     Y1, Wh, e_head_b1, e_head_w2, e_head_b2, idxb, out);
}